// Round 4
// baseline (971.067 us; speedup 1.0000x reference)
//
#include <hip/hip_runtime.h>
#include <math.h>

#define D_MODEL 4096
#define N_HEADS 32
#define D_K 128
#define MAX_SEQ 4096
#define NSPLIT 64
#define CHUNK_MAX 64
#define KV_SSTRIDE (N_HEADS * D_K)   // 4096 floats per seq position

// ws layout (floats):
//   [0      .. 4095 ]  q        (h*128+d)
//   [4096   .. 8191 ]  k_new
//   [8192   .. 12287]  v_new
//   [12288  .. 16383]  attn_out (h*128+d)
//   [16384  .. ]       partials: per (h*64+split): [m, l, o[128]]  (stride 130)
#define WS_Q      0
#define WS_KNEW   4096
#define WS_VNEW   8192
#define WS_ATTN   12288
#define WS_PART   16384
#define PART_STRIDE (2 + D_K)

// ---------------- fused QKV matvec: one wave per output row ----------------
__global__ __launch_bounds__(256) void qkv_kernel(
    const float* __restrict__ x,
    const float* __restrict__ Wq, const float* __restrict__ Wk,
    const float* __restrict__ Wv, float* __restrict__ ws)
{
    __shared__ float xs[D_MODEL];
    const int tid = threadIdx.x;
    for (int i = tid; i < D_MODEL / 4; i += 256)
        ((float4*)xs)[i] = ((const float4*)x)[i];
    __syncthreads();

    const int wid  = tid >> 6;
    const int lane = tid & 63;
    const int row_id = blockIdx.x * 4 + wid;          // 0..12287
    const int mat = row_id >> 12;                     // 0=Q 1=K 2=V
    const int row = row_id & (D_MODEL - 1);
    const float* W = (mat == 0) ? Wq : (mat == 1 ? Wk : Wv);
    const float4* wrow = (const float4*)(W + (size_t)row * D_MODEL);
    const float4* xv   = (const float4*)xs;

    float acc = 0.f;
    #pragma unroll
    for (int i = 0; i < D_MODEL / 4 / 64; ++i) {      // 16 iters
        float4 w4 = wrow[i * 64 + lane];
        float4 x4 = xv[i * 64 + lane];
        acc += w4.x * x4.x + w4.y * x4.y + w4.z * x4.z + w4.w * x4.w;
    }
    #pragma unroll
    for (int m = 32; m >= 1; m >>= 1) acc += __shfl_xor(acc, m, 64);
    if (lane == 0) ws[row_id] = acc;                  // mat*4096 + row
}

// ------------- attention flash-decode partial: (head, split) grid -------------
__global__ __launch_bounds__(256) void attn_partial_kernel(
    const float* __restrict__ kc, const float* __restrict__ vc,
    const int* __restrict__ seq_idx_p, const int* __restrict__ cur_pos_p,
    float* __restrict__ ws)
{
    const int tid   = threadIdx.x;
    const int h     = blockIdx.x >> 6;                // /NSPLIT
    const int split = blockIdx.x & (NSPLIT - 1);
    const int seq   = seq_idx_p[0];
    const int cp    = cur_pos_p[0];
    const int S     = cp + 1;
    const int chunk = (S + NSPLIT - 1) / NSPLIT;      // <=64 for S<=4096
    const int base  = split * chunk;
    int cnt = S - base;
    if (cnt > chunk) cnt = chunk;
    if (cnt < 0) cnt = 0;
    // does this split contain the freshly-written position? (wave-uniform)
    const bool has_new = (cp >= base) && (cp < base + cnt);

    float* part = ws + WS_PART + (size_t)blockIdx.x * PART_STRIDE;

    __shared__ float qs[D_K];
    __shared__ float sc[CHUNK_MAX];
    __shared__ float osum[4][D_K];
    __shared__ float m_sh, l_sh;

    if (tid < D_K / 4)
        ((float4*)qs)[tid] = ((const float4*)(ws + WS_Q + h * D_K))[tid];
    __syncthreads();

    if (cnt == 0) {   // uniform branch per block
        if (tid == 0) { part[0] = -INFINITY; part[1] = 0.f; }
        if (tid < D_K) part[2 + tid] = 0.f;
        return;
    }

    // ---- scores: one 32-lane half-wave per position, pure load-fma loop ----
    const float* kbase = kc + (size_t)seq * MAX_SEQ * KV_SSTRIDE + h * D_K;
    const int hw  = tid >> 5;        // 0..7
    const int l32 = tid & 31;
    const float4 q4 = ((const float4*)qs)[l32];
    #pragma unroll 4
    for (int i = hw; i < cnt; i += 8) {
        const float4* krow = (const float4*)(kbase + (size_t)(base + i) * KV_SSTRIDE);
        float4 k4 = krow[l32];
        float d = k4.x * q4.x + k4.y * q4.y + k4.z * q4.z + k4.w * q4.w;
        #pragma unroll
        for (int m = 16; m >= 1; m >>= 1) d += __shfl_xor(d, m, 64);
        if (l32 == 0) sc[i] = d * 0.08838834764831845f;   // 1/sqrt(128)
    }
    // barrier BEFORE the patch: the stale sc[cp-base] is written by a
    // different wave (half-wave 7); without this the patch could be
    // overwritten by the stale score (race found in round-3 audit)
    __syncthreads();
    // patch the new-token score (stale cache row was read above)
    if (has_new && tid < 32) {
        const float4* krow = (const float4*)(ws + WS_KNEW + h * D_K);
        float4 k4 = krow[l32];
        float d = k4.x * q4.x + k4.y * q4.y + k4.z * q4.z + k4.w * q4.w;
        #pragma unroll
        for (int m = 16; m >= 1; m >>= 1) d += __shfl_xor(d, m, 64);
        if (l32 == 0) sc[cp - base] = d * 0.08838834764831845f;
    }
    __syncthreads();

    // ---- block max + exp + sum (wave 0; cnt <= 64) ----
    if (tid < 64) {
        float v = (tid < cnt) ? sc[tid] : -INFINITY;
        float mm = v;
        #pragma unroll
        for (int m = 32; m >= 1; m >>= 1) mm = fmaxf(mm, __shfl_xor(mm, m, 64));
        float e = (tid < cnt) ? __expf(v - mm) : 0.f;
        sc[tid] = e;
        float L = e;
        #pragma unroll
        for (int m = 32; m >= 1; m >>= 1) L += __shfl_xor(L, m, 64);
        if (tid == 0) { m_sh = mm; l_sh = L; }
    }
    __syncthreads();

    // ---- PV: 4 position-groups, float2 per lane; pure load-fma loop ----
    const float* vbase = vc + (size_t)seq * MAX_SEQ * KV_SSTRIDE + h * D_K;
    const int grp = tid >> 6;            // 0..3
    const int dh  = tid & 63;            // float2 index within 128-dim row
    float ax = 0.f, ay = 0.f;
    #pragma unroll 4
    for (int i = grp; i < cnt; i += 4) {
        const float2* vrow = (const float2*)(vbase + (size_t)(base + i) * KV_SSTRIDE);
        float2 v2 = vrow[dh];
        float w = sc[i];
        ax += w * v2.x;
        ay += w * v2.y;
    }
    // patch new-token V contribution: subtract stale row, add fresh row
    // (race-free: same threads (grp == (cp-base)&3) did the stale read)
    if (has_new && grp == ((cp - base) & 3)) {
        const float2* vstale = (const float2*)(vbase + (size_t)cp * KV_SSTRIDE);
        const float2* vfresh = (const float2*)(ws + WS_VNEW + h * D_K);
        float2 vs = vstale[dh];
        float2 vf = vfresh[dh];
        float w = sc[cp - base];
        ax += w * (vf.x - vs.x);
        ay += w * (vf.y - vs.y);
    }
    osum[grp][dh * 2]     = ax;
    osum[grp][dh * 2 + 1] = ay;
    __syncthreads();
    if (tid < D_K)
        part[2 + tid] = osum[0][tid] + osum[1][tid] + osum[2][tid] + osum[3][tid];
    if (tid == 0) { part[0] = m_sh; part[1] = l_sh; }
}

// ---------------- combine splits per head ----------------
__global__ __launch_bounds__(128) void combine_kernel(float* __restrict__ ws)
{
    const int h   = blockIdx.x;
    const int tid = threadIdx.x;
    __shared__ float w_sh[NSPLIT];
    const float* parts = ws + WS_PART + (size_t)h * NSPLIT * PART_STRIDE;

    if (tid < 64) {
        float m = parts[tid * PART_STRIDE];           // NSPLIT==64
        float mm = m;
        #pragma unroll
        for (int k = 32; k >= 1; k >>= 1) mm = fmaxf(mm, __shfl_xor(mm, k, 64));
        float e = (m == -INFINITY) ? 0.f : __expf(m - mm);
        float l = parts[tid * PART_STRIDE + 1] * e;
        float L = l;
        #pragma unroll
        for (int k = 32; k >= 1; k >>= 1) L += __shfl_xor(L, k, 64);
        w_sh[tid] = e / L;
    }
    __syncthreads();

    float acc = 0.f;
    #pragma unroll 8
    for (int k = 0; k < NSPLIT; ++k)
        acc += w_sh[k] * parts[k * PART_STRIDE + 2 + tid];
    ws[WS_ATTN + h * D_K + tid] = acc;
}

// ---------------- output projection matvec ----------------
__global__ __launch_bounds__(256) void oproj_kernel(
    const float* __restrict__ ws, const float* __restrict__ Wo,
    float* __restrict__ out)
{
    __shared__ float xs[D_MODEL];
    const int tid = threadIdx.x;
    for (int i = tid; i < D_MODEL / 4; i += 256)
        ((float4*)xs)[i] = ((const float4*)(ws + WS_ATTN))[i];
    __syncthreads();

    const int wid  = tid >> 6;
    const int lane = tid & 63;
    const int row  = blockIdx.x * 4 + wid;
    const float4* wrow = (const float4*)(Wo + (size_t)row * D_MODEL);
    const float4* xv   = (const float4*)xs;

    float acc = 0.f;
    #pragma unroll
    for (int i = 0; i < D_MODEL / 4 / 64; ++i) {
        float4 w4 = wrow[i * 64 + lane];
        float4 x4 = xv[i * 64 + lane];
        acc += w4.x * x4.x + w4.y * x4.y + w4.z * x4.z + w4.w * x4.w;
    }
    #pragma unroll
    for (int m = 32; m >= 1; m >>= 1) acc += __shfl_xor(acc, m, 64);
    if (lane == 0) out[row] = acc;
}

extern "C" void kernel_launch(void* const* d_in, const int* in_sizes, int n_in,
                              void* d_out, int out_size, void* d_ws, size_t ws_size,
                              hipStream_t stream)
{
    const float* x   = (const float*)d_in[0];
    const int* seqi  = (const int*)d_in[1];
    const int* curp  = (const int*)d_in[2];
    const float* kc  = (const float*)d_in[3];
    const float* vc  = (const float*)d_in[4];
    const float* Wq  = (const float*)d_in[5];
    const float* Wk  = (const float*)d_in[6];
    const float* Wv  = (const float*)d_in[7];
    const float* Wo  = (const float*)d_in[8];
    float* out = (float*)d_out;
    float* ws  = (float*)d_ws;

    qkv_kernel<<<3 * D_MODEL / 4, 256, 0, stream>>>(x, Wq, Wk, Wv, ws);
    attn_partial_kernel<<<N_HEADS * NSPLIT, 256, 0, stream>>>(kc, vc, seqi, curp, ws);
    combine_kernel<<<N_HEADS, 128, 0, stream>>>(ws);
    oproj_kernel<<<D_MODEL / 4, 256, 0, stream>>>(ws, Wo, out);
}